// Round 7
// baseline (268.835 us; speedup 1.0000x reference)
//
#include <hip/hip_runtime.h>
#include <hip/hip_bf16.h>
#include <math.h>

// Problem constants: B=8, N=2048, F=128, W=64
constexpr int B = 8;
constexpr int N = 2048;
constexpr int F = 128;
constexpr int W = 64;

constexpr int TQ = 128;    // query rows per attention block (4 waves x 32q)
constexpr int TK = 64;     // key rows per K-tile iteration
constexpr int KSPLIT = 4;  // flash-decoding split over keys
constexpr int TILES_PER_SPLIT = (N / TK) / KSPLIT;   // 8

typedef short     bf16x8 __attribute__((ext_vector_type(8)));  // 8 bf16
typedef _Float16  f16x8  __attribute__((ext_vector_type(8)));  // 8 fp16
typedef float     f32x4  __attribute__((ext_vector_type(4)));  // 16x16 MFMA acc
typedef float     f32x16 __attribute__((ext_vector_type(16))); // 32x32 MFMA acc
typedef ushort    u16x8  __attribute__((ext_vector_type(8)));

__device__ inline ushort f2bf(float f) {
  union { float f; uint u; } v; v.f = f;
  uint u = v.u;
  return (ushort)((u + 0x7FFFu + ((u >> 16) & 1u)) >> 16);  // RNE
}
__device__ inline float bf2f(ushort h) {
  union { uint u; float f; } v; v.u = ((uint)h) << 16;
  return v.f;
}

// Barrier that orders LDS only (lgkmcnt), leaving global loads (vmcnt) in
// flight — __syncthreads() would drain vmcnt(0) and kill cross-tile prefetch.
__device__ inline void lgkm_barrier() {
  asm volatile("s_waitcnt lgkmcnt(0)" ::: "memory");
  __builtin_amdgcn_s_barrier();
}

// ---------------------------------------------------------------------------
// prep_w: concatenated transposed weights wt[256][128] fp16.
// wt[n][k] = W*[k][n], n in [0,64)=Q, [64,128)=K, [128,256)=V.
// Also zeroes the 128 split-merge counters each iteration (the harness
// re-poisons the workspace between iterations; prep_w is stream-ordered
// before attn, so counters are guaranteed 0 when attn runs).
// ---------------------------------------------------------------------------
__global__ __launch_bounds__(256) void prep_w(
    const float* __restrict__ wq, const float* __restrict__ wk,
    const float* __restrict__ wv, _Float16* __restrict__ wt,
    uint* __restrict__ cnt) {
  int gid = blockIdx.x * 256 + threadIdx.x;   // 4096 threads
  if (gid < B * 16) cnt[gid] = 0u;
  int n = gid >> 4;
  int k0 = (gid & 15) * 8;
  _Float16 t[8];
#pragma unroll
  for (int j = 0; j < 8; ++j) {
    int k = k0 + j;
    float val = (n < 64)  ? wq[k * W + n]
              : (n < 128) ? wk[k * W + (n - 64)]
                          : wv[k * F + (n - 128)];
    t[j] = (_Float16)val;
  }
  *(uint4*)&wt[n * 128 + k0] = *(uint4*)t;
}

// ---------------------------------------------------------------------------
// proj: fused QK+V, fp16 MFMA. One block per 32 x-rows (grid 512, 4 waves).
// XCD-pinned: block bx handles batch (bx&7) so its Q/K/V outputs land in the
// same XCD L2 that attn (also pinned by batch) will read from.
// x staged ONCE into LDS as fp16; waves 0-1 compute Q|K features (fp16 out),
// waves 2-3 compute V features stored in 32x32-MFMA B-FRAGMENT order (bf16)
// with RE-KEYED k-slot order so the attn softmax needs ZERO cross-lane ops:
//   within a 16-key group, MFMA k-slot (hB, e) holds physical key
//   (e&3) + 8*(e>>2) + 4*hB   (key bit2 <-> lane half, matching S^T layout).
//   elem V[k][f] -> frag ((b*32+kt)*4+kk2)*4 + f>>5, lane hB*32+(f&31), elem e
//   where kt=k>>6, kk2=(k>>4)&3, hB=(k>>2)&1, e=(k&3)+4*((k>>3)&1).
// ---------------------------------------------------------------------------
constexpr int KP = 136;  // 128 + 8 pad (16B align kept, 2-way banks only)

__global__ __launch_bounds__(256) void proj_kernel(
    const float* __restrict__ x, const _Float16* __restrict__ wt,
    _Float16* __restrict__ q16, _Float16* __restrict__ k16,
    ushort* __restrict__ vt_ws) {
  __shared__ _Float16 xs[32][KP];   // 8.7 KB

  const int tid  = threadIdx.x;
  const int wid  = tid >> 6;             // 0..3
  const int lane = tid & 63;
  const int lg = lane >> 4, li = lane & 15;
  const int pass = wid >> 1;             // 0 = QK, 1 = V
  const int rg   = wid & 1;              // row-group within the 32 rows
  const int bx   = blockIdx.x;
  const int b    = bx & 7;               // XCD-pinned batch
  const int nloc = (bx >> 3) * 32;
  const int brow0 = b * N + nloc;

  // stage x tile (32 x 128 fp32 -> fp16), fully coalesced
  for (int idx = tid; idx < 32 * 128 / 4; idx += 256) {
    int row = idx >> 5, c4 = idx & 31;
    float4 xv = *(const float4*)&x[(size_t)(brow0 + row) * F + c4 * 4];
    _Float16 h[4] = {(_Float16)xv.x, (_Float16)xv.y,
                     (_Float16)xv.z, (_Float16)xv.w};
    *(float2*)&xs[row][c4 * 4] = *(float2*)h;
  }
  __syncthreads();

  // x fragments for this wave's 16 rows (A/B layouts identical)
  f16x8 xa[4];
#pragma unroll
  for (int kk = 0; kk < 4; ++kk)
    xa[kk] = *(const f16x8*)&xs[rg * 16 + li][kk * 32 + lg * 8];

  f32x4 zero = {0.f, 0.f, 0.f, 0.f};
  f32x4 acc[8];
#pragma unroll
  for (int t = 0; t < 8; ++t) acc[t] = zero;

  const _Float16* wb = wt + (size_t)pass * 128 * 128;

  if (pass == 0) {
    // D[row][feat] = x . wt^T  (x as A, w as B)
#pragma unroll
    for (int kk = 0; kk < 4; ++kk)
#pragma unroll
      for (int nt = 0; nt < 8; ++nt) {
        f16x8 bw = *(const f16x8*)&wb[(nt * 16 + li) * 128 + kk * 32 + lg * 8];
        acc[nt] = __builtin_amdgcn_mfma_f32_16x16x32_f16(xa[kk], bw, acc[nt], 0, 0, 0);
      }
#pragma unroll
    for (int nt = 0; nt < 8; ++nt)
#pragma unroll
      for (int r = 0; r < 4; ++r) {
        int row = brow0 + rg * 16 + lg * 4 + r;
        int c = nt * 16 + li;
        _Float16 hv = (_Float16)acc[nt][r];
        if (nt < 4) q16[row * W + c] = hv;
        else        k16[row * W + (c - 64)] = hv;
      }
  } else {
    // D[feat][row] = (w as A) . (x as B)
#pragma unroll
    for (int kk = 0; kk < 4; ++kk)
#pragma unroll
      for (int mt = 0; mt < 8; ++mt) {
        f16x8 aw = *(const f16x8*)&wb[(mt * 16 + li) * 128 + kk * 32 + lg * 8];
        acc[mt] = __builtin_amdgcn_mfma_f32_16x16x32_f16(aw, xa[kk], acc[mt], 0, 0, 0);
      }
    // V fragment-layout store, RE-KEYED k-slot order (see header comment)
    const int n   = nloc + rg * 16 + li;      // batch-local key row
    const int kt  = n >> 6;
    const int kk2 = (n >> 4) & 3;
    const int fl  = ((n >> 2) & 1) * 32;      // lane half <- key bit2
    const int ei  = (n & 3) + 4 * ((n >> 3) & 1);   // elem <- bits 0,1,3
    ushort* vb = vt_ws + (((size_t)(b * 32 + kt) * 4 + kk2) * 4) * 512;
#pragma unroll
    for (int mt = 0; mt < 8; ++mt)
#pragma unroll
      for (int r = 0; r < 4; ++r) {
        int f = mt * 16 + lg * 4 + r;
        vb[(size_t)(f >> 5) * 512 + (size_t)(fl + (f & 31)) * 8 + ei] =
            f2bf(acc[mt][r]);
      }
  }
}

// ---------------------------------------------------------------------------
// attn: flash attention, 32x32x16 MFMA (32 queries/wave), K-split,
// unshifted softmax, S^T orientation.  Main loop IDENTICAL to the verified
// 207.3 µs R5 kernel, plus the fused split-K fixup epilogue (R6).
// R6 FAILURE FIX: R6's launch_bounds(256,2) let the compiler's occupancy
// heuristic pick 112 VGPRs (spilling oa/vreg to scratch -> 6x collapse).
// amdgpu_waves_per_eu(2,2) pins exactly 2 waves/EU -> 256-VGPR cap, no spill.
// Grid 512 x 256 threads, 2 blocks/CU, LDS 18.4 KB/block.
// ---------------------------------------------------------------------------
constexpr int LK = 72;   // 64 + 8 pad (keeps all ds ops conflict-free)

__global__ __launch_bounds__(256)
__attribute__((amdgpu_waves_per_eu(2, 2)))
void attn_kernel(
    const _Float16* __restrict__ q16, const _Float16* __restrict__ k16,
    const ushort* __restrict__ vfr,
    ushort* __restrict__ op0, ushort* __restrict__ op1,
    ushort* __restrict__ op2, ushort* __restrict__ op3,
    float* __restrict__ lsums,   // [KSPLIT][B*N]
    uint* __restrict__ cnt,      // [B*16] zeroed by prep_w
    float* __restrict__ out) {
  __shared__ _Float16 ksh[2][TK][LK];   // 18.4 KB  K tile fp16, double-buffered
  __shared__ int lastf;

  const int tid  = threadIdx.x;
  const int wid  = tid >> 6;            // 0..3
  const int lane = tid & 63;
  const int q32  = lane & 31;           // query (col) index within 32
  const int hi   = lane >> 5;           // k-half selector

  // XCD-aware swizzle: hw = xcd + 8*(qt + 16*(split)); xcd carries batch.
  const int hw    = blockIdx.x;
  const int grp   = (hw & 7) | ((hw >> 7) << 3);   // 0..31
  const int qt    = (hw >> 3) & 15;
  const int b     = grp & 7;
  const int split = grp >> 3;

  const size_t koffb = (size_t)b * N * W;
  const ushort* vfb_base = vfr + (size_t)b * 32 * 16 * 512;

  // Q fragments straight from global (this wave's 32 query rows, B-layout)
  const size_t qrow = (size_t)(b * N + qt * TQ + wid * 32 + q32) * W + hi * 8;
  f16x8 qa[4];
#pragma unroll
  for (int kk = 0; kk < 4; ++kk)
    qa[kk] = *(const f16x8*)&q16[qrow + kk * 16];

  // K staging addresses (fixed per thread): 2 b128 chunks each
  const int krow0 = tid >> 3, krow1 = krow0 + 32, kc8 = tid & 7;
  uint4 kr0, kr1;
  auto load_k = [&](int kt) {
    kr0 = *(const uint4*)&k16[koffb + ((size_t)kt * TK + krow0) * W + kc8 * 8];
    kr1 = *(const uint4*)&k16[koffb + ((size_t)kt * TK + krow1) * W + kc8 * 8];
  };

  float l_lane = 0.f;                   // denominator partial for query q32
  f32x16 oa[4];
#pragma unroll
  for (int ft = 0; ft < 4; ++ft)
#pragma unroll
    for (int r = 0; r < 16; ++r) oa[ft][r] = 0.f;

  const int kt0 = split * TILES_PER_SPLIT;
  load_k(kt0);

  for (int t = 0; t < TILES_PER_SPLIT; ++t) {
    const int kt = kt0 + t;
    const int pb = t & 1;

    // ---- V fragment loads for THIS tile (global, coalesced, no LDS) ----
    const ushort* vfb = vfb_base + (size_t)kt * 16 * 512 + (size_t)lane * 8;
    uint4 vreg[16];
#pragma unroll
    for (int kk2 = 0; kk2 < 4; ++kk2) {
      const ushort* vb2 = vfb + kk2 * 2048;
      vreg[kk2 * 4 + 0] = *(const uint4*)&vb2[0];
      vreg[kk2 * 4 + 1] = *(const uint4*)&vb2[512];
      vreg[kk2 * 4 + 2] = *(const uint4*)&vb2[1024];
      vreg[kk2 * 4 + 3] = *(const uint4*)&vb2[1536];
    }

    // ---- drain K prefetch regs into LDS buffer pb, issue next K loads ----
    *(uint4*)&ksh[pb][krow0][kc8 * 8] = kr0;
    *(uint4*)&ksh[pb][krow1][kc8 * 8] = kr1;
    if (t + 1 < TILES_PER_SPLIT) load_k(kt + 1);

    // single barrier per tile: ksh[pb] visible; vmcnt stays outstanding
    lgkm_barrier();

    // ---- S^T = K Q^T : 32x32x16 f16, 2 key-subtiles x 4 k-steps ----
    f32x16 s2[2];
#pragma unroll
    for (int mt = 0; mt < 2; ++mt)
#pragma unroll
      for (int r = 0; r < 16; ++r) s2[mt][r] = 0.f;
    __builtin_amdgcn_s_setprio(1);
#pragma unroll
    for (int kk = 0; kk < 4; ++kk)
#pragma unroll
      for (int mt = 0; mt < 2; ++mt) {
        f16x8 kf = *(const f16x8*)&ksh[pb][mt * 32 + q32][kk * 16 + hi * 8];
        s2[mt] = __builtin_amdgcn_mfma_f32_32x32x16_f16(kf, qa[kk], s2[mt], 0, 0, 0);
      }
    __builtin_amdgcn_s_setprio(0);

    // ---- softmax: pure-register. Lane holds 32 keys of query q32 with
    // key = mt*32 + (r&3) + 8*(r>>2) + 4*hi.  V's re-keyed k-slot order
    // makes pk(pf[8g+2i], pf[8g+2i+1]) directly the PV A-frag words. ----
    uint4 paw[4];                        // A-frags for kk2 = 0..3
#pragma unroll
    for (int mt = 0; mt < 2; ++mt) {
      float pf[16];
#pragma unroll
      for (int r = 0; r < 16; ++r) pf[r] = __expf(s2[mt][r]);
      float t0 = (pf[0] + pf[1]) + (pf[2] + pf[3]);
      float t1 = (pf[4] + pf[5]) + (pf[6] + pf[7]);
      float t2 = (pf[8] + pf[9]) + (pf[10] + pf[11]);
      float t3 = (pf[12] + pf[13]) + (pf[14] + pf[15]);
      l_lane += (t0 + t1) + (t2 + t3);
#pragma unroll
      for (int gm = 0; gm < 2; ++gm) {
        uint w0, w1, w2, w3;
        asm("v_cvt_pk_bf16_f32 %0, %1, %2" : "=v"(w0) : "v"(pf[gm * 8 + 0]), "v"(pf[gm * 8 + 1]));
        asm("v_cvt_pk_bf16_f32 %0, %1, %2" : "=v"(w1) : "v"(pf[gm * 8 + 2]), "v"(pf[gm * 8 + 3]));
        asm("v_cvt_pk_bf16_f32 %0, %1, %2" : "=v"(w2) : "v"(pf[gm * 8 + 4]), "v"(pf[gm * 8 + 5]));
        asm("v_cvt_pk_bf16_f32 %0, %1, %2" : "=v"(w3) : "v"(pf[gm * 8 + 6]), "v"(pf[gm * 8 + 7]));
        paw[mt * 2 + gm] = make_uint4(w0, w1, w2, w3);
      }
    }

    // ---- O += P V : both operands straight from registers ----
    __builtin_amdgcn_s_setprio(1);
#pragma unroll
    for (int g = 0; g < 4; ++g) {
      bf16x8 pa = __builtin_bit_cast(bf16x8, paw[g]);
#pragma unroll
      for (int ft = 0; ft < 4; ++ft) {
        bf16x8 vf = __builtin_bit_cast(bf16x8, vreg[g * 4 + ft]);
        oa[ft] = __builtin_amdgcn_mfma_f32_32x32x16_bf16(pa, vf, oa[ft], 0, 0, 0);
      }
    }
    __builtin_amdgcn_s_setprio(0);
  }

  // ---- finish l: halves of each query row live in lane and lane^32 ----
  l_lane += __shfl_xor(l_lane, 32, 64);

  // ---- epilogue: store UNNORMALIZED bf16 partial + l per row ----
  ushort* opb = (split == 0) ? op0 : (split == 1) ? op1 : (split == 2) ? op2 : op3;
  ushort* ob = opb + (size_t)(b * N + qt * TQ + wid * 32) * F;
#pragma unroll
  for (int ft = 0; ft < 4; ++ft)
#pragma unroll
    for (int r = 0; r < 16; ++r) {
      int qr = (r & 3) + 8 * (r >> 2) + 4 * hi;
      ob[(size_t)qr * F + ft * 32 + q32] = f2bf(oa[ft][r]);
    }
  if (hi == 0) {
    size_t gr = (size_t)split * B * N + (size_t)(b * N + qt * TQ) + wid * 32 + q32;
    lsums[gr] = l_lane;
  }

  // ---- split-K fixup: last split block of this (b,qt) merges ----
  __threadfence();                       // release: partials visible
  if (tid == 0) {
    uint old = atomicAdd(&cnt[b * 16 + qt], 1u);
    lastf = (old == 3u);
  }
  __syncthreads();
  if (lastf) {
    __threadfence();                     // acquire: order reads after atomic
    constexpr size_t BN = (size_t)B * N;
    const size_t gr0 = (size_t)b * N + (size_t)qt * TQ;
    // 128 rows x 16 col-groups = 2048 units; 8 per thread
#pragma unroll
    for (int u = 0; u < 8; ++u) {
      const int unit = tid + u * 256;
      const int row = unit >> 4;
      const int c8 = (unit & 15) * 8;
      const size_t gr = gr0 + row;
      const float l = lsums[gr] + lsums[BN + gr] +
                      lsums[2 * BN + gr] + lsums[3 * BN + gr];
      const float inv = 1.f / l;
      const size_t base = gr * F + c8;
      u16x8 a0 = *(const u16x8*)&op0[base];
      u16x8 a1 = *(const u16x8*)&op1[base];
      u16x8 a2 = *(const u16x8*)&op2[base];
      u16x8 a3 = *(const u16x8*)&op3[base];
      float o[8];
#pragma unroll
      for (int j = 0; j < 8; ++j)
        o[j] = (bf2f(a0[j]) + bf2f(a1[j]) + bf2f(a2[j]) + bf2f(a3[j])) * inv;
      *(float4*)&out[base]     = *(float4*)&o[0];
      *(float4*)&out[base + 4] = *(float4*)&o[4];
    }
  }
}

// ---------------------------------------------------------------------------
// Launch
// ---------------------------------------------------------------------------
extern "C" void kernel_launch(void* const* d_in, const int* in_sizes, int n_in,
                              void* d_out, int out_size, void* d_ws, size_t ws_size,
                              hipStream_t stream) {
  // setup_inputs order: x, adj(unused), w_key, w_value, w_query
  const float* x  = (const float*)d_in[0];
  const float* wk = (const float*)d_in[2];
  const float* wv = (const float*)d_in[3];
  const float* wq = (const float*)d_in[4];
  float* out = (float*)d_out;

  constexpr size_t BNW = (size_t)B * N * W;   // 1,048,576
  constexpr size_t BNF = (size_t)B * N * F;   // 2,097,152
  _Float16* q16 = (_Float16*)d_ws;            // BNW fp16
  _Float16* k16 = q16 + BNW;                  // BNW fp16
  ushort*   vt  = (ushort*)(k16 + BNW);       // BNF u16 (V fragments)
  _Float16* wt  = (_Float16*)(vt + BNF);      // 256*128 fp16
  ushort*   op0 = (ushort*)(wt + 32768);      // BNF u16 partials x4
  ushort*   op1 = op0 + BNF;
  ushort*   op2 = op1 + BNF;
  ushort*   op3 = op2 + BNF;
  float*    ls  = (float*)(op3 + BNF);        // KSPLIT*B*N fp32
  uint*     cnt = (uint*)(ls + (size_t)KSPLIT * B * N);  // 128 u32
  // total ~25 MB

  prep_w<<<16, 256, 0, stream>>>(wq, wk, wv, wt, cnt);
  proj_kernel<<<(B * N) / 32, 256, 0, stream>>>(x, wt, q16, k16, vt);
  attn_kernel<<<dim3(512), 256, 0, stream>>>(q16, k16, vt, op0, op1, op2, op3,
                                             ls, cnt, out);
}

// Round 8
// 206.325 us; speedup vs baseline: 1.3030x; 1.3030x over previous
//
#include <hip/hip_runtime.h>
#include <hip/hip_bf16.h>
#include <math.h>

// Problem constants: B=8, N=2048, F=128, W=64
constexpr int B = 8;
constexpr int N = 2048;
constexpr int F = 128;
constexpr int W = 64;

constexpr int TQ = 128;    // query rows per attention block (4 waves x 32q)
constexpr int TK = 64;     // key rows per K-tile iteration
constexpr int KSPLIT = 4;  // flash-decoding split over keys
constexpr int TILES_PER_SPLIT = (N / TK) / KSPLIT;   // 8

typedef short     bf16x8 __attribute__((ext_vector_type(8)));  // 8 bf16
typedef _Float16  f16x8  __attribute__((ext_vector_type(8)));  // 8 fp16
typedef float     f32x4  __attribute__((ext_vector_type(4)));  // 16x16 MFMA acc
typedef float     f32x16 __attribute__((ext_vector_type(16))); // 32x32 MFMA acc
typedef ushort    u16x8  __attribute__((ext_vector_type(8)));

__device__ inline ushort f2bf(float f) {
  union { float f; uint u; } v; v.f = f;
  uint u = v.u;
  return (ushort)((u + 0x7FFFu + ((u >> 16) & 1u)) >> 16);  // RNE
}
__device__ inline float bf2f(ushort h) {
  union { uint u; float f; } v; v.u = ((uint)h) << 16;
  return v.f;
}

// Barrier that orders LDS only (lgkmcnt), leaving global loads (vmcnt) in
// flight — __syncthreads() would drain vmcnt(0) and kill cross-tile prefetch.
__device__ inline void lgkm_barrier() {
  asm volatile("s_waitcnt lgkmcnt(0)" ::: "memory");
  __builtin_amdgcn_s_barrier();
}

// ---------------------------------------------------------------------------
// prep_w: concatenated transposed weights wt[256][128] fp16.
// wt[n][k] = W*[k][n], n in [0,64)=Q, [64,128)=K, [128,256)=V.
// ---------------------------------------------------------------------------
__global__ __launch_bounds__(256) void prep_w(
    const float* __restrict__ wq, const float* __restrict__ wk,
    const float* __restrict__ wv, _Float16* __restrict__ wt) {
  int gid = blockIdx.x * 256 + threadIdx.x;   // 4096 threads
  int n = gid >> 4;
  int k0 = (gid & 15) * 8;
  _Float16 t[8];
#pragma unroll
  for (int j = 0; j < 8; ++j) {
    int k = k0 + j;
    float val = (n < 64)  ? wq[k * W + n]
              : (n < 128) ? wk[k * W + (n - 64)]
                          : wv[k * F + (n - 128)];
    t[j] = (_Float16)val;
  }
  *(uint4*)&wt[n * 128 + k0] = *(uint4*)t;
}

// ---------------------------------------------------------------------------
// proj: fused QK+V, fp16 MFMA. One block per 32 x-rows (grid 512, 4 waves).
// XCD-pinned: block bx handles batch (bx&7) so its Q/K/V outputs land in the
// same XCD L2 that attn (also pinned by batch) will read from.
// x staged ONCE into LDS as fp16; waves 0-1 compute Q|K features (fp16 out),
// waves 2-3 compute V features stored in 32x32-MFMA B-FRAGMENT order (bf16)
// with RE-KEYED k-slot order so the attn softmax needs ZERO cross-lane ops:
//   within a 16-key group, MFMA k-slot (hB, e) holds physical key
//   (e&3) + 8*(e>>2) + 4*hB   (key bit2 <-> lane half, matching S^T layout).
//   elem V[k][f] -> frag ((b*32+kt)*4+kk2)*4 + f>>5, lane hB*32+(f&31), elem e
//   where kt=k>>6, kk2=(k>>4)&3, hB=(k>>2)&1, e=(k&3)+4*((k>>3)&1).
// ---------------------------------------------------------------------------
constexpr int KP = 136;  // 128 + 8 pad (16B align kept, 2-way banks only)

__global__ __launch_bounds__(256) void proj_kernel(
    const float* __restrict__ x, const _Float16* __restrict__ wt,
    _Float16* __restrict__ q16, _Float16* __restrict__ k16,
    ushort* __restrict__ vt_ws) {
  __shared__ _Float16 xs[32][KP];   // 8.7 KB

  const int tid  = threadIdx.x;
  const int wid  = tid >> 6;             // 0..3
  const int lane = tid & 63;
  const int lg = lane >> 4, li = lane & 15;
  const int pass = wid >> 1;             // 0 = QK, 1 = V
  const int rg   = wid & 1;              // row-group within the 32 rows
  const int bx   = blockIdx.x;
  const int b    = bx & 7;               // XCD-pinned batch
  const int nloc = (bx >> 3) * 32;
  const int brow0 = b * N + nloc;

  // stage x tile (32 x 128 fp32 -> fp16), fully coalesced
  for (int idx = tid; idx < 32 * 128 / 4; idx += 256) {
    int row = idx >> 5, c4 = idx & 31;
    float4 xv = *(const float4*)&x[(size_t)(brow0 + row) * F + c4 * 4];
    _Float16 h[4] = {(_Float16)xv.x, (_Float16)xv.y,
                     (_Float16)xv.z, (_Float16)xv.w};
    *(float2*)&xs[row][c4 * 4] = *(float2*)h;
  }
  __syncthreads();

  // x fragments for this wave's 16 rows (A/B layouts identical)
  f16x8 xa[4];
#pragma unroll
  for (int kk = 0; kk < 4; ++kk)
    xa[kk] = *(const f16x8*)&xs[rg * 16 + li][kk * 32 + lg * 8];

  f32x4 zero = {0.f, 0.f, 0.f, 0.f};
  f32x4 acc[8];
#pragma unroll
  for (int t = 0; t < 8; ++t) acc[t] = zero;

  const _Float16* wb = wt + (size_t)pass * 128 * 128;

  if (pass == 0) {
    // D[row][feat] = x . wt^T  (x as A, w as B)
#pragma unroll
    for (int kk = 0; kk < 4; ++kk)
#pragma unroll
      for (int nt = 0; nt < 8; ++nt) {
        f16x8 bw = *(const f16x8*)&wb[(nt * 16 + li) * 128 + kk * 32 + lg * 8];
        acc[nt] = __builtin_amdgcn_mfma_f32_16x16x32_f16(xa[kk], bw, acc[nt], 0, 0, 0);
      }
#pragma unroll
    for (int nt = 0; nt < 8; ++nt)
#pragma unroll
      for (int r = 0; r < 4; ++r) {
        int row = brow0 + rg * 16 + lg * 4 + r;
        int c = nt * 16 + li;
        _Float16 hv = (_Float16)acc[nt][r];
        if (nt < 4) q16[row * W + c] = hv;
        else        k16[row * W + (c - 64)] = hv;
      }
  } else {
    // D[feat][row] = (w as A) . (x as B)
#pragma unroll
    for (int kk = 0; kk < 4; ++kk)
#pragma unroll
      for (int mt = 0; mt < 8; ++mt) {
        f16x8 aw = *(const f16x8*)&wb[(mt * 16 + li) * 128 + kk * 32 + lg * 8];
        acc[mt] = __builtin_amdgcn_mfma_f32_16x16x32_f16(aw, xa[kk], acc[mt], 0, 0, 0);
      }
    // V fragment-layout store, RE-KEYED k-slot order (see header comment)
    const int n   = nloc + rg * 16 + li;      // batch-local key row
    const int kt  = n >> 6;
    const int kk2 = (n >> 4) & 3;
    const int fl  = ((n >> 2) & 1) * 32;      // lane half <- key bit2
    const int ei  = (n & 3) + 4 * ((n >> 3) & 1);   // elem <- bits 0,1,3
    ushort* vb = vt_ws + (((size_t)(b * 32 + kt) * 4 + kk2) * 4) * 512;
#pragma unroll
    for (int mt = 0; mt < 8; ++mt)
#pragma unroll
      for (int r = 0; r < 4; ++r) {
        int f = mt * 16 + lg * 4 + r;
        vb[(size_t)(f >> 5) * 512 + (size_t)(fl + (f & 31)) * 8 + ei] =
            f2bf(acc[mt][r]);
      }
  }
}

// ---------------------------------------------------------------------------
// attn: flash attention, 32x32x16 MFMA (32 queries/wave), K-split,
// unshifted softmax, S^T orientation.
//  - K staged via double-buffered LDS -> ONE lgkm barrier per tile
//  - V read directly from global in re-keyed fragment order (no LDS),
//    issued at loop top so L2 latency hides under QK^T + softmax
//  - P never leaves registers: S^T register layout == PV A-frag key order
//    (V re-keyed to match), so softmax is 32 exp + 16 v_cvt_pk_bf16_f32
//    and ZERO cross-lane / LDS traffic.
//  - XCD swizzle: each XCD owns one batch (K/V/Q working set ~1MB -> L2-hot)
// Grid 512 x 256 threads, 2 blocks/CU, LDS 18.4 KB/block.
// NOTE (R6/R7 lesson): fusing the split-K merge into this kernel's epilogue
// (atomic counter tail) makes hipcc collapse the allocation to ~108 VGPR and
// re-materialize/spill the V-fragment state -> 6x slowdown. Keep combine
// as a separate dispatch.
// ---------------------------------------------------------------------------
constexpr int LK = 72;   // 64 + 8 pad (keeps all ds ops conflict-free)

__global__ __launch_bounds__(256, 2) void attn_kernel(
    const _Float16* __restrict__ q16, const _Float16* __restrict__ k16,
    const ushort* __restrict__ vfr,
    ushort* __restrict__ op0, ushort* __restrict__ op1,
    ushort* __restrict__ op2, ushort* __restrict__ op3,
    float* __restrict__ lsums) {  // [KSPLIT][B*N]
  __shared__ _Float16 ksh[2][TK][LK];   // 18.4 KB  K tile fp16, double-buffered

  const int tid  = threadIdx.x;
  const int wid  = tid >> 6;            // 0..3
  const int lane = tid & 63;
  const int q32  = lane & 31;           // query (col) index within 32
  const int hi   = lane >> 5;           // k-half selector

  // XCD-aware swizzle: hw = xcd + 8*(qt + 16*(split)); xcd carries batch.
  const int hw    = blockIdx.x;
  const int grp   = (hw & 7) | ((hw >> 7) << 3);   // 0..31
  const int qt    = (hw >> 3) & 15;
  const int b     = grp & 7;
  const int split = grp >> 3;

  const size_t koffb = (size_t)b * N * W;
  const ushort* vfb_base = vfr + (size_t)b * 32 * 16 * 512;

  // Q fragments straight from global (this wave's 32 query rows, B-layout)
  const size_t qrow = (size_t)(b * N + qt * TQ + wid * 32 + q32) * W + hi * 8;
  f16x8 qa[4];
#pragma unroll
  for (int kk = 0; kk < 4; ++kk)
    qa[kk] = *(const f16x8*)&q16[qrow + kk * 16];

  // K staging addresses (fixed per thread): 2 b128 chunks each
  const int krow0 = tid >> 3, krow1 = krow0 + 32, kc8 = tid & 7;
  uint4 kr0, kr1;
  auto load_k = [&](int kt) {
    kr0 = *(const uint4*)&k16[koffb + ((size_t)kt * TK + krow0) * W + kc8 * 8];
    kr1 = *(const uint4*)&k16[koffb + ((size_t)kt * TK + krow1) * W + kc8 * 8];
  };

  float l_lane = 0.f;                   // denominator partial for query q32
  f32x16 oa[4];
#pragma unroll
  for (int ft = 0; ft < 4; ++ft)
#pragma unroll
    for (int r = 0; r < 16; ++r) oa[ft][r] = 0.f;

  const int kt0 = split * TILES_PER_SPLIT;
  load_k(kt0);

  for (int t = 0; t < TILES_PER_SPLIT; ++t) {
    const int kt = kt0 + t;
    const int pb = t & 1;

    // ---- V fragment loads for THIS tile (global, coalesced, no LDS) ----
    const ushort* vfb = vfb_base + (size_t)kt * 16 * 512 + (size_t)lane * 8;
    uint4 vreg[16];
#pragma unroll
    for (int kk2 = 0; kk2 < 4; ++kk2) {
      const ushort* vb2 = vfb + kk2 * 2048;
      vreg[kk2 * 4 + 0] = *(const uint4*)&vb2[0];
      vreg[kk2 * 4 + 1] = *(const uint4*)&vb2[512];
      vreg[kk2 * 4 + 2] = *(const uint4*)&vb2[1024];
      vreg[kk2 * 4 + 3] = *(const uint4*)&vb2[1536];
    }

    // ---- drain K prefetch regs into LDS buffer pb, issue next K loads ----
    *(uint4*)&ksh[pb][krow0][kc8 * 8] = kr0;
    *(uint4*)&ksh[pb][krow1][kc8 * 8] = kr1;
    if (t + 1 < TILES_PER_SPLIT) load_k(kt + 1);

    // single barrier per tile: ksh[pb] visible; vmcnt stays outstanding
    lgkm_barrier();

    // ---- S^T = K Q^T : 32x32x16 f16, 2 key-subtiles x 4 k-steps ----
    f32x16 s2[2];
#pragma unroll
    for (int mt = 0; mt < 2; ++mt)
#pragma unroll
      for (int r = 0; r < 16; ++r) s2[mt][r] = 0.f;
    __builtin_amdgcn_s_setprio(1);
#pragma unroll
    for (int kk = 0; kk < 4; ++kk)
#pragma unroll
      for (int mt = 0; mt < 2; ++mt) {
        f16x8 kf = *(const f16x8*)&ksh[pb][mt * 32 + q32][kk * 16 + hi * 8];
        s2[mt] = __builtin_amdgcn_mfma_f32_32x32x16_f16(kf, qa[kk], s2[mt], 0, 0, 0);
      }
    __builtin_amdgcn_s_setprio(0);

    // ---- softmax: pure-register. Lane holds 32 keys of query q32 with
    // key = mt*32 + (r&3) + 8*(r>>2) + 4*hi.  V's re-keyed k-slot order
    // makes pk(pf[8g+2i], pf[8g+2i+1]) directly the PV A-frag words. ----
    uint4 paw[4];                        // A-frags for kk2 = 0..3
#pragma unroll
    for (int mt = 0; mt < 2; ++mt) {
      float pf[16];
#pragma unroll
      for (int r = 0; r < 16; ++r) pf[r] = __expf(s2[mt][r]);
      float t0 = (pf[0] + pf[1]) + (pf[2] + pf[3]);
      float t1 = (pf[4] + pf[5]) + (pf[6] + pf[7]);
      float t2 = (pf[8] + pf[9]) + (pf[10] + pf[11]);
      float t3 = (pf[12] + pf[13]) + (pf[14] + pf[15]);
      l_lane += (t0 + t1) + (t2 + t3);
#pragma unroll
      for (int gm = 0; gm < 2; ++gm) {
        uint w0, w1, w2, w3;
        asm("v_cvt_pk_bf16_f32 %0, %1, %2" : "=v"(w0) : "v"(pf[gm * 8 + 0]), "v"(pf[gm * 8 + 1]));
        asm("v_cvt_pk_bf16_f32 %0, %1, %2" : "=v"(w1) : "v"(pf[gm * 8 + 2]), "v"(pf[gm * 8 + 3]));
        asm("v_cvt_pk_bf16_f32 %0, %1, %2" : "=v"(w2) : "v"(pf[gm * 8 + 4]), "v"(pf[gm * 8 + 5]));
        asm("v_cvt_pk_bf16_f32 %0, %1, %2" : "=v"(w3) : "v"(pf[gm * 8 + 6]), "v"(pf[gm * 8 + 7]));
        paw[mt * 2 + gm] = make_uint4(w0, w1, w2, w3);
      }
    }

    // ---- O += P V : both operands straight from registers ----
    __builtin_amdgcn_s_setprio(1);
#pragma unroll
    for (int g = 0; g < 4; ++g) {
      bf16x8 pa = __builtin_bit_cast(bf16x8, paw[g]);
#pragma unroll
      for (int ft = 0; ft < 4; ++ft) {
        bf16x8 vf = __builtin_bit_cast(bf16x8, vreg[g * 4 + ft]);
        oa[ft] = __builtin_amdgcn_mfma_f32_32x32x16_bf16(pa, vf, oa[ft], 0, 0, 0);
      }
    }
    __builtin_amdgcn_s_setprio(0);
  }

  // ---- finish l: halves of each query row live in lane and lane^32 ----
  l_lane += __shfl_xor(l_lane, 32, 64);

  // ---- epilogue: store UNNORMALIZED bf16 partial + l per row ----
  ushort* opb = (split == 0) ? op0 : (split == 1) ? op1 : (split == 2) ? op2 : op3;
  ushort* ob = opb + (size_t)(b * N + qt * TQ + wid * 32) * F;
#pragma unroll
  for (int ft = 0; ft < 4; ++ft)
#pragma unroll
    for (int r = 0; r < 16; ++r) {
      int qr = (r & 3) + 8 * (r >> 2) + 4 * hi;
      ob[(size_t)qr * F + ft * 32 + q32] = f2bf(oa[ft][r]);
    }
  if (hi == 0) {
    size_t gr = (size_t)split * B * N + (size_t)(b * N + qt * TQ) + wid * 32 + q32;
    lsums[gr] = l_lane;
  }
}

// ---------------------------------------------------------------------------
// combine: merge the four bf16 K-split partials. Vectorized (uint4 loads,
// float4 stores). XCD-pinned: block bx handles rows of batch (bx&7), whose
// partials were written by attn on that same XCD -> L2 hits.
// ---------------------------------------------------------------------------
__global__ __launch_bounds__(256) void combine_kernel(
    const ushort* __restrict__ op0, const ushort* __restrict__ op1,
    const ushort* __restrict__ op2, const ushort* __restrict__ op3,
    const float* __restrict__ lsums, float* __restrict__ out) {
  const int bx = blockIdx.x;                 // 1024 blocks, 16 rows each
  const int gr = (bx & 7) * N + (bx >> 3) * 16 + (threadIdx.x >> 4);
  const int c8 = (threadIdx.x & 15) * 8;
  constexpr size_t BN = (size_t)B * N;
  const float l = lsums[gr] + lsums[BN + gr] + lsums[2 * BN + gr] + lsums[3 * BN + gr];
  const float inv = 1.f / l;
  const size_t base = (size_t)gr * F + c8;
  u16x8 a0 = *(const u16x8*)&op0[base];
  u16x8 a1 = *(const u16x8*)&op1[base];
  u16x8 a2 = *(const u16x8*)&op2[base];
  u16x8 a3 = *(const u16x8*)&op3[base];
  float o[8];
#pragma unroll
  for (int j = 0; j < 8; ++j)
    o[j] = (bf2f(a0[j]) + bf2f(a1[j]) + bf2f(a2[j]) + bf2f(a3[j])) * inv;
  *(float4*)&out[base]     = *(float4*)&o[0];
  *(float4*)&out[base + 4] = *(float4*)&o[4];
}

// ---------------------------------------------------------------------------
// Launch
// ---------------------------------------------------------------------------
extern "C" void kernel_launch(void* const* d_in, const int* in_sizes, int n_in,
                              void* d_out, int out_size, void* d_ws, size_t ws_size,
                              hipStream_t stream) {
  // setup_inputs order: x, adj(unused), w_key, w_value, w_query
  const float* x  = (const float*)d_in[0];
  const float* wk = (const float*)d_in[2];
  const float* wv = (const float*)d_in[3];
  const float* wq = (const float*)d_in[4];
  float* out = (float*)d_out;

  constexpr size_t BNW = (size_t)B * N * W;   // 1,048,576
  constexpr size_t BNF = (size_t)B * N * F;   // 2,097,152
  _Float16* q16 = (_Float16*)d_ws;            // BNW fp16
  _Float16* k16 = q16 + BNW;                  // BNW fp16
  ushort*   vt  = (ushort*)(k16 + BNW);       // BNF u16 (V fragments)
  _Float16* wt  = (_Float16*)(vt + BNF);      // 256*128 fp16
  ushort*   op0 = (ushort*)(wt + 32768);      // BNF u16 partials x4
  ushort*   op1 = op0 + BNF;
  ushort*   op2 = op1 + BNF;
  ushort*   op3 = op2 + BNF;
  float*    ls  = (float*)(op3 + BNF);        // KSPLIT*B*N fp32
  // total ~25 MB

  prep_w<<<16, 256, 0, stream>>>(wq, wk, wv, wt);
  proj_kernel<<<(B * N) / 32, 256, 0, stream>>>(x, wt, q16, k16, vt);
  attn_kernel<<<dim3(512), 256, 0, stream>>>(q16, k16, vt, op0, op1, op2, op3, ls);
  combine_kernel<<<(B * N) / 16, 256, 0, stream>>>(op0, op1, op2, op3, ls, out);
}